// Round 3
// baseline (14575.122 us; speedup 1.0000x reference)
//
#include <hip/hip_runtime.h>

// Spiking self-attention (Spikformer SSA) forward — streamed over T.
// Precision-hardened: double accumulation in GEMM/BN stats, numpy-matching
// elementwise rounding (no FMA contraction) in LIF/BN-apply chains.
// Shapes: T=16, B=8, N=196, C=512, H=8, hd=64.

#define TT 16
#define BB 8
#define NNQ 196
#define CC 512
#define HH 8
#define HD 64
#define O3 1536
#define BN (BB*NNQ)          // 1568 rows per t
#define PT (BN*CC)           // 802816 elems per t

static constexpr float VTH = 0.5f;

__device__ __forceinline__ float sigm(float w){ return 1.f/(1.f+expf(-w)); }

// LIF step matching np rounding: v = v + (x - v)*sg ; spike ; hard reset.
__device__ __forceinline__ float lif_step(float x, float& v, float sg){
  float d  = __fsub_rn(x, v);
  float dd = __fmul_rn(d, sg);
  v = __fadd_rn(v, dd);
  float sp = (v >= VTH) ? 1.f : 0.f;
  v = __fmul_rn(v, __fsub_rn(1.f, sp));   // exact: *0 or *1
  return sp;
}

// ---- LIF single step on x_t: [B,N,C]; state vin ----
__global__ void k_lif_x(const float* __restrict__ xt, const float* __restrict__ w,
                        float* __restrict__ vin, float* __restrict__ s0, int first){
  int g = blockIdx.x*256 + threadIdx.x;
  float sg = sigm(w[0]);
  float v = first ? 0.f : vin[g];
  float sp = lif_step(xt[g], v, sg);
  s0[g] = sp;
  vin[g] = v;
}

// ---- C[M=1568,ON] = A[1568,512]*W[ON,512]^T + bias, double accumulation ----
template<int ON>
__global__ void k_gemm_nt(const float* __restrict__ A, const float* __restrict__ W,
                          const float* __restrict__ bias, float* __restrict__ Cm){
  const int M = BN;
  __shared__ float As[64][17];
  __shared__ float Ws[64][17];
  int tx = threadIdx.x, ty = threadIdx.y;
  int lid = ty*16 + tx;
  int lr = lid>>2, lc = (lid&3)<<2;
  int m0 = blockIdx.x*64, o0 = blockIdx.y*64;
  double acc[4][4] = {};
  for (int k0=0;k0<CC;k0+=16){
    int ar = m0 + lr; if (ar >= M) ar = M-1;
    float4 av = *reinterpret_cast<const float4*>(&A[(size_t)ar*CC + k0 + lc]);
    float4 wv = *reinterpret_cast<const float4*>(&W[(size_t)(o0+lr)*CC + k0 + lc]);
    As[lr][lc+0]=av.x; As[lr][lc+1]=av.y; As[lr][lc+2]=av.z; As[lr][lc+3]=av.w;
    Ws[lr][lc+0]=wv.x; Ws[lr][lc+1]=wv.y; Ws[lr][lc+2]=wv.z; Ws[lr][lc+3]=wv.w;
    __syncthreads();
    #pragma unroll
    for (int kk=0;kk<16;++kk){
      float a[4], b[4];
      #pragma unroll
      for (int i=0;i<4;++i) a[i]=As[ty*4+i][kk];
      #pragma unroll
      for (int j=0;j<4;++j) b[j]=Ws[tx*4+j][kk];
      #pragma unroll
      for (int i=0;i<4;++i)
        #pragma unroll
        for (int j=0;j<4;++j) acc[i][j] += (double)a[i]*(double)b[j];
    }
    __syncthreads();
  }
  #pragma unroll
  for (int i=0;i<4;++i){
    int m = m0 + ty*4 + i;
    if (m >= M) break;
    #pragma unroll
    for (int j=0;j<4;++j){
      int o = o0 + tx*4 + j;
      Cm[(size_t)m*ON + o] = (float)(acc[i][j] + (double)bias[o]);
    }
  }
}

// ---- BN1 stats for this t: X [1568,1536] -> mean/rstd [1536], double acc ----
__global__ void k_bn1_stats(const float* __restrict__ X, float* __restrict__ mean,
                            float* __restrict__ rstd){
  int o = blockIdx.x*64 + threadIdx.x;
  double sum=0.0, sq=0.0;
  for (int i=threadIdx.y; i<BN; i+=4){
    double v = (double)X[(size_t)i*O3 + o];
    sum += v; sq += v*v;
  }
  __shared__ double ssum[4][64], ssq[4][64];
  ssum[threadIdx.y][threadIdx.x]=sum;
  ssq [threadIdx.y][threadIdx.x]=sq;
  __syncthreads();
  if (threadIdx.y==0){
    double s = ssum[0][threadIdx.x]+ssum[1][threadIdx.x]+ssum[2][threadIdx.x]+ssum[3][threadIdx.x];
    double q = ssq [0][threadIdx.x]+ssq [1][threadIdx.x]+ssq [2][threadIdx.x]+ssq [3][threadIdx.x];
    double m = s*(1.0/BN);
    double var = q*(1.0/BN) - m*m;
    mean[o]=(float)m;
    rstd[o]=(float)(1.0/sqrt(var+1e-5));
  }
}

// ---- BN1-normalize + LIF step for q/k/v; spikes out in [B,H,N,hd] ----
__global__ void k_lif_qkv(const float* __restrict__ qkv, const float* __restrict__ mean,
                          const float* __restrict__ rstd, const float* __restrict__ g1,
                          const float* __restrict__ b1,
                          const float* __restrict__ wq, const float* __restrict__ wk,
                          const float* __restrict__ wv,
                          float* __restrict__ vq, float* __restrict__ vk, float* __restrict__ vv,
                          float* __restrict__ qs, float* __restrict__ ks,
                          float* __restrict__ vs, int t, int first){
  int g = blockIdx.x*256 + threadIdx.x;   // (b,h,n,d) flat
  int j = blockIdx.y;                      // 0:q 1:k 2:v
  int d = g & 63;
  int n = (g>>6) % NNQ;
  int h = (g/(NNQ*64)) & 7;
  int b = g/(NNQ*64*8);
  int o = j*CC + h*HD + d;
  const float* w = (j==0)? wq : (j==1)? wk : wv;
  float* st  = (j==0)? vq : (j==1)? vk : vv;
  float* out = (j==0)? qs : (j==1)? ks : vs;
  float sg = sigm(w[0]);
  float xv = qkv[(size_t)(b*NNQ + n)*O3 + o];
  // ((x-m)*rstd)*g + b, each op rounded (matches np)
  float xn = __fadd_rn(__fmul_rn(__fmul_rn(__fsub_rn(xv, mean[o]), rstd[o]),
                                 g1[t*O3+o]), b1[t*O3+o]);
  float v = first ? 0.f : st[g];
  float sp = lif_step(xn, v, sg);
  out[g] = sp;
  st[g] = v;
}

// ---- per (b,h): kv[d,e]=sum_n k*v (LDS), attn[n,e]=0.125*sum_d q*kv ----
// All values are small integers -> exact in fp32 in any order.
__global__ void k_kvqv(const float* __restrict__ ks, const float* __restrict__ vs,
                       const float* __restrict__ qs, float* __restrict__ attn){
  int blk = blockIdx.x;            // (b,h)
  int base = blk * (NNQ*HD);
  __shared__ float kvs[64][64];
  __shared__ float kt[32][64];
  __shared__ float vt[32][64];
  int tid = threadIdx.x;
  int d = tid>>2, e0 = (tid&3)<<4;
  float acc[16] = {};
  for (int n0=0;n0<NNQ;n0+=32){
    int nn = (NNQ-n0 < 32) ? (NNQ-n0) : 32;
    for (int l=tid; l<nn*64; l+=256){
      kt[l>>6][l&63] = ks[base + n0*64 + l];
      vt[l>>6][l&63] = vs[base + n0*64 + l];
    }
    __syncthreads();
    for (int r=0;r<nn;++r){
      float kk = kt[r][d];
      #pragma unroll
      for (int e=0;e<16;++e) acc[e] += kk*vt[r][e0+e];
    }
    __syncthreads();
  }
  #pragma unroll
  for (int e=0;e<16;++e) kvs[d][e0+e] = acc[e];
  __syncthreads();
  int e = tid & 63, grp = tid >> 6;
  for (int n=grp; n<NNQ; n+=4){
    float a = 0.f;
    #pragma unroll
    for (int dd=0; dd<64; ++dd) a += qs[base + n*64 + dd]*kvs[dd][e];
    attn[base + n*64 + e] = a * 0.125f;   // exact (power of 2 scale)
  }
}

// ---- LIF step on attention out [B,H,N,hd] -> spikes in [(B,N),C] layout ----
__global__ void k_lif_attn(const float* __restrict__ ain, const float* __restrict__ w,
                           float* __restrict__ vo, float* __restrict__ sp, int first){
  int g = blockIdx.x*256 + threadIdx.x;   // (b,h,n,e) flat
  int e = g & 63;
  int n = (g>>6) % NNQ;
  int h = (g/(NNQ*64)) & 7;
  int b = g/(NNQ*64*8);
  float sg = sigm(w[0]);
  float v = first ? 0.f : vo[g];
  float s = lif_step(ain[g], v, sg);
  sp[(size_t)(b*NNQ + n)*CC + h*HD + e] = s;
  vo[g] = v;
}

// ---- BN2 fused stats(double)+apply: X [1568,512] -> Y ----
__global__ void k_bn2(const float* __restrict__ X, const float* __restrict__ g2,
                      const float* __restrict__ b2, float* __restrict__ Y, int t){
  int c = blockIdx.x*64 + threadIdx.x;   // 0..511
  double sum=0.0, sq=0.0;
  for (int i=threadIdx.y; i<BN; i+=4){
    double v = (double)X[(size_t)i*CC + c];
    sum += v; sq += v*v;
  }
  __shared__ double ssum[4][64], ssq[4][64];
  ssum[threadIdx.y][threadIdx.x]=sum;
  ssq [threadIdx.y][threadIdx.x]=sq;
  __syncthreads();
  double s = ssum[0][threadIdx.x]+ssum[1][threadIdx.x]+ssum[2][threadIdx.x]+ssum[3][threadIdx.x];
  double q = ssq [0][threadIdx.x]+ssq [1][threadIdx.x]+ssq [2][threadIdx.x]+ssq [3][threadIdx.x];
  double m = s*(1.0/BN);
  double var = q*(1.0/BN) - m*m;
  float mf = (float)m;
  float rstd = (float)(1.0/sqrt(var+1e-5));
  float gg = g2[t*CC+c];
  float bb = b2[t*CC+c];
  for (int i=threadIdx.y; i<BN; i+=4){
    float xv = X[(size_t)i*CC + c];
    Y[(size_t)i*CC + c] =
      __fadd_rn(__fmul_rn(__fmul_rn(__fsub_rn(xv, mf), rstd), gg), bb);
  }
}

extern "C" void kernel_launch(void* const* d_in, const int* in_sizes, int n_in,
                              void* d_out, int out_size, void* d_ws, size_t ws_size,
                              hipStream_t stream){
  const float* x      = (const float*)d_in[0];
  const float* qkv_w  = (const float*)d_in[1];
  const float* qkv_b  = (const float*)d_in[2];
  const float* bn1_g  = (const float*)d_in[3];
  const float* bn1_b  = (const float*)d_in[4];
  const float* proj_w = (const float*)d_in[5];
  const float* proj_b = (const float*)d_in[6];
  const float* bn2_g  = (const float*)d_in[7];
  const float* bn2_b  = (const float*)d_in[8];
  const float* w_in   = (const float*)d_in[9];
  const float* w_q    = (const float*)d_in[10];
  const float* w_k    = (const float*)d_in[11];
  const float* w_v    = (const float*)d_in[12];
  const float* w_proj = (const float*)d_in[13];
  float* outp = (float*)d_out;
  float* ws = (float*)d_ws;

  float* vin   = ws + 0*(size_t)PT;
  float* vq    = ws + 1*(size_t)PT;
  float* vk    = ws + 2*(size_t)PT;
  float* vv    = ws + 3*(size_t)PT;
  float* vo    = ws + 4*(size_t)PT;
  float* s0    = ws + 5*(size_t)PT;
  float* qkvt  = ws + 6*(size_t)PT;   // [1568,1536] (3*PT)
  float* qt    = ws + 9*(size_t)PT;
  float* kt    = ws + 10*(size_t)PT;
  float* vt    = ws + 11*(size_t)PT;
  float* attnt = ws + 12*(size_t)PT;
  float* sproj = ws + 13*(size_t)PT;
  float* projo = ws + 14*(size_t)PT;
  float* mean1 = ws + 15*(size_t)PT;
  float* rstd1 = mean1 + O3;

  for (int t=0; t<TT; ++t){
    const float* xt = x + (size_t)t*PT;
    float* outt = outp + (size_t)t*PT;
    int first = (t==0) ? 1 : 0;

    k_lif_x<<<PT/256, 256, 0, stream>>>(xt, w_in, vin, s0, first);

    k_gemm_nt<O3><<<dim3(25, O3/64), dim3(16,16), 0, stream>>>(s0, qkv_w, qkv_b, qkvt);

    k_bn1_stats<<<O3/64, dim3(64,4), 0, stream>>>(qkvt, mean1, rstd1);

    k_lif_qkv<<<dim3(PT/256, 3), 256, 0, stream>>>(qkvt, mean1, rstd1, bn1_g, bn1_b,
                                                   w_q, w_k, w_v, vq, vk, vv,
                                                   qt, kt, vt, t, first);

    k_kvqv<<<BB*HH, 256, 0, stream>>>(kt, vt, qt, attnt);

    k_lif_attn<<<PT/256, 256, 0, stream>>>(attnt, w_proj, vo, sproj, first);

    k_gemm_nt<CC><<<dim3(25, CC/64), dim3(16,16), 0, stream>>>(sproj, proj_w, proj_b, projo);

    k_bn2<<<CC/64, dim3(64,4), 0, stream>>>(projo, bn2_g, bn2_b, outt, t);
  }
}

// Round 4
// 4927.248 us; speedup vs baseline: 2.9581x; 2.9581x over previous
//
#include <hip/hip_runtime.h>

// Spiking self-attention (Spikformer SSA) forward — T-batched with runtime
// chunking by ws_size. Spikes stored as u8. fp64-accumulated GEMM/BN stats,
// numpy-matched elementwise rounding. T=16,B=8,N=196,C=512,H=8,hd=64.

#define TT 16
#define BB 8
#define NNQ 196
#define CC 512
#define HH 8
#define HD 64
#define O3 1536
#define BN (BB*NNQ)          // 1568 rows per t
#define PT (BN*CC)           // 802816 elems per t
#define BHND (NNQ*HD)        // 12544 per (b,h)

static constexpr float VTH = 0.5f;

__device__ __forceinline__ float sigm(float w){ return 1.f/(1.f+expf(-w)); }

// LIF step matching np rounding: v += (x-v)*sg ; spike ; hard reset (exact).
__device__ __forceinline__ float lif_step(float x, float& v, float sg){
  float d  = __fsub_rn(x, v);
  float dd = __fmul_rn(d, sg);
  v = __fadd_rn(v, dd);
  float sp = (v >= VTH) ? 1.f : 0.f;
  v = __fmul_rn(v, __fsub_rn(1.f, sp));
  return sp;
}

// ---- LIF scan on input x: lane owns (b,n,c), scans tc steps ----
__global__ void k_lif_x(const float* __restrict__ x, const float* __restrict__ w,
                        float* __restrict__ vin, unsigned char* __restrict__ s0,
                        int t0, int tc){
  int g = blockIdx.x*256 + threadIdx.x;
  float sg = sigm(w[0]);
  float v = (t0==0) ? 0.f : vin[g];
  for (int tt=0; tt<tc; ++tt){
    float sp = lif_step(x[(size_t)(t0+tt)*PT + g], v, sg);
    s0[(size_t)tt*PT + g] = (unsigned char)sp;
  }
  vin[g] = v;
}

// ---- C[M,ON] = A[M,512](u8) * W[ON,512]^T + bias, fp64 accumulate ----
template<int ON>
__global__ void k_gemm_nt(const unsigned char* __restrict__ A, const float* __restrict__ W,
                          const float* __restrict__ bias, float* __restrict__ Cm, int M){
  __shared__ double As[64][17];
  __shared__ double Ws[64][17];
  int tx = threadIdx.x, ty = threadIdx.y;
  int lid = ty*16 + tx;
  int lr = lid>>2, lc = (lid&3)<<2;
  int m0 = blockIdx.x*64, o0 = blockIdx.y*64;
  double acc[4][4] = {};
  for (int k0=0;k0<CC;k0+=16){
    int ar = m0 + lr; if (ar >= M) ar = M-1;
    uchar4 av = *reinterpret_cast<const uchar4*>(&A[(size_t)ar*CC + k0 + lc]);
    float4 wv = *reinterpret_cast<const float4*>(&W[(size_t)(o0+lr)*CC + k0 + lc]);
    As[lr][lc+0]=(double)av.x; As[lr][lc+1]=(double)av.y;
    As[lr][lc+2]=(double)av.z; As[lr][lc+3]=(double)av.w;
    Ws[lr][lc+0]=(double)wv.x; Ws[lr][lc+1]=(double)wv.y;
    Ws[lr][lc+2]=(double)wv.z; Ws[lr][lc+3]=(double)wv.w;
    __syncthreads();
    #pragma unroll
    for (int kk=0;kk<16;++kk){
      double a[4], b[4];
      #pragma unroll
      for (int i=0;i<4;++i) a[i]=As[ty*4+i][kk];
      #pragma unroll
      for (int j=0;j<4;++j) b[j]=Ws[tx*4+j][kk];
      #pragma unroll
      for (int i=0;i<4;++i)
        #pragma unroll
        for (int j=0;j<4;++j) acc[i][j] += a[i]*b[j];
    }
    __syncthreads();
  }
  #pragma unroll
  for (int i=0;i<4;++i){
    int m = m0 + ty*4 + i;
    if (m >= M) break;
    #pragma unroll
    for (int j=0;j<4;++j){
      int o = o0 + tx*4 + j;
      Cm[(size_t)m*ON + o] = (float)(acc[i][j] + (double)bias[o]);
    }
  }
}

// ---- BN1 stats: per (tt,o) over 1568 rows, fp64 ----
__global__ void k_bn1_stats(const float* __restrict__ X, float* __restrict__ mean,
                            float* __restrict__ rstd){
  int o = blockIdx.x*64 + threadIdx.x;
  int tt = blockIdx.y;
  const float* Xb = X + (size_t)tt*BN*O3;
  double sum=0.0, sq=0.0;
  for (int i=threadIdx.y; i<BN; i+=4){
    double v = (double)Xb[(size_t)i*O3 + o];
    sum += v; sq += v*v;
  }
  __shared__ double ssum[4][64], ssq[4][64];
  ssum[threadIdx.y][threadIdx.x]=sum;
  ssq [threadIdx.y][threadIdx.x]=sq;
  __syncthreads();
  if (threadIdx.y==0){
    double s = ssum[0][threadIdx.x]+ssum[1][threadIdx.x]+ssum[2][threadIdx.x]+ssum[3][threadIdx.x];
    double q = ssq [0][threadIdx.x]+ssq [1][threadIdx.x]+ssq [2][threadIdx.x]+ssq [3][threadIdx.x];
    double m = s*(1.0/BN);
    double var = q*(1.0/BN) - m*m;
    mean[tt*O3+o]=(float)m;
    rstd[tt*O3+o]=(float)(1.0/sqrt(var+1e-5));
  }
}

// ---- BN1-normalize + LIF scan for q/k/v; spikes u8 out in [tt,b,h,n,d] ----
__global__ void k_lif_qkv(const float* __restrict__ qkv, const float* __restrict__ mean,
                          const float* __restrict__ rstd, const float* __restrict__ g1,
                          const float* __restrict__ b1,
                          const float* __restrict__ wq, const float* __restrict__ wk,
                          const float* __restrict__ wv,
                          float* __restrict__ vq, float* __restrict__ vk, float* __restrict__ vv,
                          unsigned char* __restrict__ qs, unsigned char* __restrict__ ks,
                          unsigned char* __restrict__ vs, int t0, int tc){
  int g = blockIdx.x*256 + threadIdx.x;   // (b,h,n,d) flat
  int j = blockIdx.y;                      // 0:q 1:k 2:v
  int d = g & 63;
  int n = (g>>6) % NNQ;
  int h = (g/(NNQ*64)) & 7;
  int b = g/(NNQ*64*8);
  int o = j*CC + h*HD + d;
  const float* w = (j==0)? wq : (j==1)? wk : wv;
  float* st  = (j==0)? vq : (j==1)? vk : vv;
  unsigned char* out = (j==0)? qs : (j==1)? ks : vs;
  float sg = sigm(w[0]);
  float v = (t0==0) ? 0.f : st[g];
  size_t row = (size_t)(b*NNQ + n)*O3 + o;
  for (int tt=0; tt<tc; ++tt){
    float xv = qkv[(size_t)tt*BN*O3 + row];
    int so = tt*O3 + o;
    int go = (t0+tt)*O3 + o;
    float xn = __fadd_rn(__fmul_rn(__fmul_rn(__fsub_rn(xv, mean[so]), rstd[so]),
                                   g1[go]), b1[go]);
    float sp = lif_step(xn, v, sg);
    out[(size_t)tt*PT + g] = (unsigned char)sp;
  }
  st[g] = v;
}

// ---- per (tt,b,h): kv[d,e]=sum_n k*v (LDS), attn[n,e]=0.125*sum_d q*kv ----
// Spike values are small integers -> exact fp32 in any order.
__global__ void k_kvqv(const unsigned char* __restrict__ ks, const unsigned char* __restrict__ vs,
                       const unsigned char* __restrict__ qs, float* __restrict__ attn){
  int blk = blockIdx.x;            // tt*64 + (b,h)
  size_t base = (size_t)blk * BHND;
  __shared__ float kvs[64][64];
  __shared__ float kt[32][64];
  __shared__ float vt[32][64];
  int tid = threadIdx.x;
  int d = tid>>2, e0 = (tid&3)<<4;
  float acc[16] = {};
  for (int n0=0;n0<NNQ;n0+=32){
    int nn = (NNQ-n0 < 32) ? (NNQ-n0) : 32;
    for (int l=tid; l<nn*64; l+=256){
      kt[l>>6][l&63] = (float)ks[base + n0*64 + l];
      vt[l>>6][l&63] = (float)vs[base + n0*64 + l];
    }
    __syncthreads();
    for (int r=0;r<nn;++r){
      float kk = kt[r][d];
      #pragma unroll
      for (int e=0;e<16;++e) acc[e] += kk*vt[r][e0+e];
    }
    __syncthreads();
  }
  #pragma unroll
  for (int e=0;e<16;++e) kvs[d][e0+e] = acc[e];
  __syncthreads();
  int e = tid & 63, grp = tid >> 6;
  for (int n=grp; n<NNQ; n+=4){
    float a = 0.f;
    #pragma unroll
    for (int dd=0; dd<64; ++dd) a += (float)qs[base + n*64 + dd]*kvs[dd][e];
    attn[base + n*64 + e] = a * 0.125f;   // exact pow2 scale
  }
}

// ---- LIF scan on attention out; spikes u8 out in [tt,(b,n),C] ----
__global__ void k_lif_attn(const float* __restrict__ ain, const float* __restrict__ w,
                           float* __restrict__ vo, unsigned char* __restrict__ sp,
                           int t0, int tc){
  int g = blockIdx.x*256 + threadIdx.x;   // (b,h,n,e) flat
  int e = g & 63;
  int n = (g>>6) % NNQ;
  int h = (g/(NNQ*64)) & 7;
  int b = g/(NNQ*64*8);
  size_t dst = (size_t)(b*NNQ + n)*CC + h*HD + e;
  float sg = sigm(w[0]);
  float v = (t0==0) ? 0.f : vo[g];
  for (int tt=0; tt<tc; ++tt){
    float s = lif_step(ain[(size_t)tt*PT + g], v, sg);
    sp[(size_t)tt*PT + dst] = (unsigned char)s;
  }
  vo[g] = v;
}

// ---- BN2 fused stats(fp64)+apply per (tt,c); writes final output ----
__global__ void k_bn2(const float* __restrict__ X, const float* __restrict__ g2,
                      const float* __restrict__ b2, float* __restrict__ Y, int t0){
  int c = blockIdx.x*64 + threadIdx.x;   // 0..511
  int tt = blockIdx.y;
  const float* Xb = X + (size_t)tt*(size_t)BN*CC;
  float* Yb = Y + (size_t)(t0+tt)*PT;
  double sum=0.0, sq=0.0;
  for (int i=threadIdx.y; i<BN; i+=4){
    double v = (double)Xb[(size_t)i*CC + c];
    sum += v; sq += v*v;
  }
  __shared__ double ssum[4][64], ssq[4][64];
  ssum[threadIdx.y][threadIdx.x]=sum;
  ssq [threadIdx.y][threadIdx.x]=sq;
  __syncthreads();
  double s = ssum[0][threadIdx.x]+ssum[1][threadIdx.x]+ssum[2][threadIdx.x]+ssum[3][threadIdx.x];
  double q = ssq [0][threadIdx.x]+ssq [1][threadIdx.x]+ssq [2][threadIdx.x]+ssq [3][threadIdx.x];
  double m = s*(1.0/BN);
  double var = q*(1.0/BN) - m*m;
  float mf = (float)m;
  float rs = (float)(1.0/sqrt(var+1e-5));
  float gg = g2[(t0+tt)*CC+c];
  float bb = b2[(t0+tt)*CC+c];
  for (int i=threadIdx.y; i<BN; i+=4){
    float xv = Xb[(size_t)i*CC + c];
    Yb[(size_t)i*CC + c] =
      __fadd_rn(__fmul_rn(__fmul_rn(__fsub_rn(xv, mf), rs), gg), bb);
  }
}

extern "C" void kernel_launch(void* const* d_in, const int* in_sizes, int n_in,
                              void* d_out, int out_size, void* d_ws, size_t ws_size,
                              hipStream_t stream){
  const float* x      = (const float*)d_in[0];
  const float* qkv_w  = (const float*)d_in[1];
  const float* qkv_b  = (const float*)d_in[2];
  const float* bn1_g  = (const float*)d_in[3];
  const float* bn1_b  = (const float*)d_in[4];
  const float* proj_w = (const float*)d_in[5];
  const float* proj_b = (const float*)d_in[6];
  const float* bn2_g  = (const float*)d_in[7];
  const float* bn2_b  = (const float*)d_in[8];
  const float* w_in   = (const float*)d_in[9];
  const float* w_q    = (const float*)d_in[10];
  const float* w_k    = (const float*)d_in[11];
  const float* w_v    = (const float*)d_in[12];
  const float* w_proj = (const float*)d_in[13];
  float* outp = (float*)d_out;

  // bytes needed = 16MB states + TC * 20.08MB
  auto need = [](int tc)->size_t{
    return 4ull*5*PT + 8ull*tc*O3
         + 4ull*tc*BN*O3 + 4ull*tc*PT + 4ull*tc*PT   // qkv_all, attn, projo
         + 5ull*tc*PT;                               // 5 u8 spike bufs
  };
  int TC = 16;
  while (TC > 1 && need(TC) > ws_size) TC >>= 1;

  char* p = (char*)d_ws;
  float* vin = (float*)p; p += 4ull*PT;
  float* vq  = (float*)p; p += 4ull*PT;
  float* vk  = (float*)p; p += 4ull*PT;
  float* vv  = (float*)p; p += 4ull*PT;
  float* vo  = (float*)p; p += 4ull*PT;
  float* mean1 = (float*)p; p += 4ull*TC*O3;
  float* rstd1 = (float*)p; p += 4ull*TC*O3;
  float* qkv_all = (float*)p; p += 4ull*TC*BN*O3;
  float* attn    = (float*)p; p += 4ull*TC*PT;
  float* projo   = (float*)p; p += 4ull*TC*PT;
  unsigned char* s0    = (unsigned char*)p; p += (size_t)TC*PT;
  unsigned char* qs    = (unsigned char*)p; p += (size_t)TC*PT;
  unsigned char* ksb   = (unsigned char*)p; p += (size_t)TC*PT;
  unsigned char* vsb   = (unsigned char*)p; p += (size_t)TC*PT;
  unsigned char* sproj = (unsigned char*)p; p += (size_t)TC*PT;

  for (int t0=0; t0<TT; t0+=TC){
    int M = TC*BN;
    k_lif_x<<<PT/256, 256, 0, stream>>>(x, w_in, vin, s0, t0, TC);

    k_gemm_nt<O3><<<dim3((M+63)/64, O3/64), dim3(16,16), 0, stream>>>(s0, qkv_w, qkv_b, qkv_all, M);

    k_bn1_stats<<<dim3(O3/64, TC), dim3(64,4), 0, stream>>>(qkv_all, mean1, rstd1);

    k_lif_qkv<<<dim3(PT/256, 3), 256, 0, stream>>>(qkv_all, mean1, rstd1, bn1_g, bn1_b,
                                                   w_q, w_k, w_v, vq, vk, vv,
                                                   qs, ksb, vsb, t0, TC);

    k_kvqv<<<TC*BB*HH, 256, 0, stream>>>(ksb, vsb, qs, attn);

    k_lif_attn<<<PT/256, 256, 0, stream>>>(attn, w_proj, vo, sproj, t0, TC);

    k_gemm_nt<CC><<<dim3((M+63)/64, CC/64), dim3(16,16), 0, stream>>>(sproj, proj_w, proj_b, projo, M);

    k_bn2<<<dim3(CC/64, TC), dim3(64,4), 0, stream>>>(projo, bn2_g, bn2_b, outp, t0);
  }
}

// Round 5
// 893.458 us; speedup vs baseline: 16.3132x; 5.5148x over previous
//
#include <hip/hip_runtime.h>

// Spiking self-attention (Spikformer SSA) forward — MFMA everywhere.
// Spikes/kv are exact in bf16; weights 3-way bf16 split (hi+mid+lo, residual
// ~2^-27) so GEMM matches fp32-exact numerics to ~1e-7. T-chunked by ws_size.
// T=16,B=8,N=196,C=512,H=8,hd=64.

#define TT 16
#define BB 8
#define NNQ 196
#define CC 512
#define HH 8
#define HD 64
#define O3 1536
#define BN (BB*NNQ)          // 1568
#define PT (BN*CC)           // 802816
#define WTOT ((O3+CC)*CC)    // 1048576 split-weight elems

static constexpr float VTH = 0.5f;
typedef __attribute__((ext_vector_type(8))) short short8;
typedef __attribute__((ext_vector_type(4))) float f32x4;
typedef unsigned short u16;

__device__ __forceinline__ float sigm(float w){ return 1.f/(1.f+expf(-w)); }

__device__ __forceinline__ float lif_step(float x, float& v, float sg){
  float d  = __fsub_rn(x, v);
  float dd = __fmul_rn(d, sg);
  v = __fadd_rn(v, dd);
  float sp = (v >= VTH) ? 1.f : 0.f;
  v = __fmul_rn(v, __fsub_rn(1.f, sp));
  return sp;
}

__device__ __forceinline__ u16 bf16_rn(float x){
  unsigned u = __float_as_uint(x);
  unsigned r = u + 0x7FFF + ((u>>16)&1);
  return (u16)(r>>16);
}
__device__ __forceinline__ float bf16_to_f(u16 h){
  return __uint_as_float(((unsigned)h)<<16);
}

// ---- split weights into hi/mid/lo bf16 ----
__global__ void k_wsplit(const float* __restrict__ qkv_w, const float* __restrict__ proj_w,
                         u16* __restrict__ whi, u16* __restrict__ wmid, u16* __restrict__ wlo){
  int i = blockIdx.x*256 + threadIdx.x;
  float w = (i < O3*CC) ? qkv_w[i] : proj_w[i - O3*CC];
  u16 h = bf16_rn(w);          float r1 = w - bf16_to_f(h);
  u16 m = bf16_rn(r1);         float r2 = r1 - bf16_to_f(m);
  u16 l = bf16_rn(r2);
  whi[i]=h; wmid[i]=m; wlo[i]=l;
}

// ---- LIF scan on input x -> bf16 spikes ----
__global__ void k_lif_x(const float* __restrict__ x, const float* __restrict__ w,
                        float* __restrict__ vin, u16* __restrict__ s0, int t0, int tc){
  int g = blockIdx.x*256 + threadIdx.x;
  float sg = sigm(w[0]);
  float v = (t0==0) ? 0.f : vin[g];
  for (int tt=0; tt<tc; ++tt){
    float sp = lif_step(x[(size_t)(t0+tt)*PT + g], v, sg);
    s0[(size_t)tt*PT + g] = (sp!=0.f) ? 0x3F80 : 0;
  }
  vin[g] = v;
}

// ---- C[M,ON] = A(bf16 0/1)[M,512] * (Whi+Wmid+Wlo)[ON,512]^T + bias ----
template<int ON>
__global__ __launch_bounds__(256)
void k_gemm_mfma(const u16* __restrict__ A, const u16* __restrict__ Wh,
                 const u16* __restrict__ Wm, const u16* __restrict__ Wl,
                 const float* __restrict__ bias, float* __restrict__ Cm, int M){
  __shared__ __align__(16) u16 Al[128][64];
  __shared__ __align__(16) u16 Bh[128][64];
  __shared__ __align__(16) u16 Bm[128][64];
  __shared__ __align__(16) u16 Bl[128][64];
  int tid = threadIdx.x;
  int w = tid>>6, lane = tid&63;
  int m0 = blockIdx.x*128, o0 = blockIdx.y*128;
  int wm = (w&1)*64, wn = (w>>1)*64;
  int r16 = lane&15, kg = lane>>4;
  f32x4 acc[4][4] = {};
  for (int k0=0;k0<512;k0+=64){
    #pragma unroll
    for (int i=0;i<4;++i){
      int u = tid*4 + i;            // 0..1023
      int row = u>>3, slot = u&7;
      int sl = slot ^ (row&7);
      int gr = m0+row; if (gr>=M) gr=M-1;
      *(float4*)&Al[row][sl*8] = *(const float4*)&A [(size_t)gr*512      + k0 + slot*8];
      *(float4*)&Bh[row][sl*8] = *(const float4*)&Wh[(size_t)(o0+row)*512 + k0 + slot*8];
      *(float4*)&Bm[row][sl*8] = *(const float4*)&Wm[(size_t)(o0+row)*512 + k0 + slot*8];
      *(float4*)&Bl[row][sl*8] = *(const float4*)&Wl[(size_t)(o0+row)*512 + k0 + slot*8];
    }
    __syncthreads();
    #pragma unroll
    for (int s=0;s<2;++s){
      short8 af[4], bh[4], bm[4], bl[4];
      #pragma unroll
      for (int mt=0;mt<4;++mt){
        int r = wm + mt*16 + r16;
        af[mt] = *(const short8*)&Al[r][((s*4+kg)^(r&7))*8];
      }
      #pragma unroll
      for (int nt=0;nt<4;++nt){
        int r = wn + nt*16 + r16;
        int sl = ((s*4+kg)^(r&7))*8;
        bh[nt] = *(const short8*)&Bh[r][sl];
        bm[nt] = *(const short8*)&Bm[r][sl];
        bl[nt] = *(const short8*)&Bl[r][sl];
      }
      #pragma unroll
      for (int mt=0;mt<4;++mt)
        #pragma unroll
        for (int nt=0;nt<4;++nt){
          acc[mt][nt] = __builtin_amdgcn_mfma_f32_16x16x32_bf16(af[mt], bh[nt], acc[mt][nt],0,0,0);
          acc[mt][nt] = __builtin_amdgcn_mfma_f32_16x16x32_bf16(af[mt], bm[nt], acc[mt][nt],0,0,0);
          acc[mt][nt] = __builtin_amdgcn_mfma_f32_16x16x32_bf16(af[mt], bl[nt], acc[mt][nt],0,0,0);
        }
    }
    __syncthreads();
  }
  #pragma unroll
  for (int mt=0; mt<4; ++mt)
    #pragma unroll
    for (int nt=0; nt<4; ++nt){
      int o = o0 + wn + nt*16 + r16;
      float bs = bias[o];
      #pragma unroll
      for (int i=0;i<4;++i){
        int m = m0 + wm + mt*16 + kg*4 + i;
        if (m < M) Cm[(size_t)m*ON + o] = acc[mt][nt][i] + bs;
      }
    }
}

// ---- BN1 stats per (tt,o), fp64 ----
__global__ void k_bn1_stats(const float* __restrict__ X, float* __restrict__ mean,
                            float* __restrict__ rstd){
  int o = blockIdx.x*64 + threadIdx.x;
  int tt = blockIdx.y;
  const float* Xb = X + (size_t)tt*BN*O3;
  double sum=0.0, sq=0.0;
  for (int i=threadIdx.y; i<BN; i+=4){
    double v = (double)Xb[(size_t)i*O3 + o];
    sum += v; sq += v*v;
  }
  __shared__ double ssum[4][64], ssq[4][64];
  ssum[threadIdx.y][threadIdx.x]=sum;
  ssq [threadIdx.y][threadIdx.x]=sq;
  __syncthreads();
  if (threadIdx.y==0){
    double s = ssum[0][threadIdx.x]+ssum[1][threadIdx.x]+ssum[2][threadIdx.x]+ssum[3][threadIdx.x];
    double q = ssq [0][threadIdx.x]+ssq [1][threadIdx.x]+ssq [2][threadIdx.x]+ssq [3][threadIdx.x];
    double m = s*(1.0/BN);
    double var = q*(1.0/BN) - m*m;
    mean[tt*O3+o]=(float)m;
    rstd[tt*O3+o]=(float)(1.0/sqrt(var+1e-5));
  }
}

// ---- BN1 + LIF scan q/k/v -> bf16 spikes [tt,b,h,n,d] ----
__global__ void k_lif_qkv(const float* __restrict__ qkv, const float* __restrict__ mean,
                          const float* __restrict__ rstd, const float* __restrict__ g1,
                          const float* __restrict__ b1,
                          const float* __restrict__ wq, const float* __restrict__ wk,
                          const float* __restrict__ wv,
                          float* __restrict__ vq, float* __restrict__ vk, float* __restrict__ vv,
                          u16* __restrict__ qs, u16* __restrict__ ks,
                          u16* __restrict__ vs, int t0, int tc){
  int g = blockIdx.x*256 + threadIdx.x;
  int j = blockIdx.y;
  int d = g & 63;
  int n = (g>>6) % NNQ;
  int h = (g/(NNQ*64)) & 7;
  int b = g/(NNQ*64*8);
  int o = j*CC + h*HD + d;
  const float* w = (j==0)? wq : (j==1)? wk : wv;
  float* st  = (j==0)? vq : (j==1)? vk : vv;
  u16* out = (j==0)? qs : (j==1)? ks : vs;
  float sg = sigm(w[0]);
  float v = (t0==0) ? 0.f : st[g];
  size_t row = (size_t)(b*NNQ + n)*O3 + o;
  for (int tt=0; tt<tc; ++tt){
    float xv = qkv[(size_t)tt*BN*O3 + row];
    int so = tt*O3 + o;
    int go = (t0+tt)*O3 + o;
    float xn = __fadd_rn(__fmul_rn(__fmul_rn(__fsub_rn(xv, mean[so]), rstd[so]),
                                   g1[go]), b1[go]);
    float sp = lif_step(xn, v, sg);
    out[(size_t)tt*PT + g] = (sp!=0.f) ? 0x3F80 : 0;
  }
  st[g] = v;
}

// ---- per (tt,b,h): kv = K^T V (MFMA), then attn = 0.125 * Q kv (MFMA) ----
__global__ __launch_bounds__(256)
void k_kvqv_mfma(const u16* __restrict__ ks, const u16* __restrict__ vs,
                 const u16* __restrict__ qs, float* __restrict__ attn){
  __shared__ __align__(16) u16 Kb[224][64];
  __shared__ __align__(16) u16 Vb[224][64];
  __shared__ __align__(16) u16 kvb[64][64];
  int blk = blockIdx.x;
  size_t base = (size_t)blk * (NNQ*HD);
  int tid = threadIdx.x, w = tid>>6, lane = tid&63;
  int r16 = lane&15, kg = lane>>4;
  // stage K,V (zero-pad rows 196..223)
  for (int u=tid; u<224*8; u+=256){
    int row=u>>3, slot=u&7;
    float4 z = {0.f,0.f,0.f,0.f};
    float4 kd = z, vd = z;
    if (row < NNQ){
      kd = *(const float4*)&ks[base + (size_t)row*64 + slot*8];
      vd = *(const float4*)&vs[base + (size_t)row*64 + slot*8];
    }
    *(float4*)&Kb[row][slot*8] = kd;
    *(float4*)&Vb[row][slot*8] = vd;
  }
  __syncthreads();
  // phase 1: kv[d][e] = sum_n K[n][d] V[n][e]; wave w owns d-tile w
  f32x4 acc[4] = {};
  int d0 = w*16;
  for (int n0=0;n0<224;n0+=32){
    short8 af;
    #pragma unroll
    for (int jj=0;jj<8;++jj) af[jj] = (short)Kb[n0+kg*8+jj][d0 + r16];
    #pragma unroll
    for (int nt=0;nt<4;++nt){
      short8 bf;
      #pragma unroll
      for (int jj=0;jj<8;++jj) bf[jj] = (short)Vb[n0+kg*8+jj][nt*16 + r16];
      acc[nt] = __builtin_amdgcn_mfma_f32_16x16x32_bf16(af, bf, acc[nt],0,0,0);
    }
  }
  // kv -> bf16 in LDS (values are exact ints <= 196)
  #pragma unroll
  for (int nt=0;nt<4;++nt)
    #pragma unroll
    for (int i=0;i<4;++i)
      kvb[d0 + kg*4 + i][nt*16 + r16] = (u16)(__float_as_uint(acc[nt][i])>>16);
  __syncthreads();
  // stage Q into Kb, XOR-swizzled rows (for b128 frag reads)
  for (int u=tid; u<224*8; u+=256){
    int row=u>>3, slot=u&7;
    int sl = slot ^ (row&7);
    float4 qd = {0.f,0.f,0.f,0.f};
    if (row < NNQ) qd = *(const float4*)&qs[base + (size_t)row*64 + slot*8];
    *(float4*)&Kb[row][sl*8] = qd;
  }
  __syncthreads();
  // phase 2: attn[n][e] = 0.125 * sum_d Q[n][d] kv[d][e]
  short8 bkv[2][4];
  #pragma unroll
  for (int s=0;s<2;++s)
    #pragma unroll
    for (int nt=0;nt<4;++nt){
      short8 bf;
      #pragma unroll
      for (int jj=0;jj<8;++jj) bf[jj] = (short)kvb[s*32 + kg*8 + jj][nt*16 + r16];
      bkv[s][nt] = bf;
    }
  for (int mt=w; mt<13; mt+=4){
    f32x4 a2[4] = {};
    short8 qa[2];
    #pragma unroll
    for (int s=0;s<2;++s){
      int r = mt*16 + r16;
      qa[s] = *(const short8*)&Kb[r][(((s*4+kg)^(r&7)))*8];
    }
    #pragma unroll
    for (int s=0;s<2;++s)
      #pragma unroll
      for (int nt=0;nt<4;++nt)
        a2[nt] = __builtin_amdgcn_mfma_f32_16x16x32_bf16(qa[s], bkv[s][nt], a2[nt],0,0,0);
    #pragma unroll
    for (int nt=0;nt<4;++nt){
      int e = nt*16 + r16;
      #pragma unroll
      for (int i=0;i<4;++i){
        int n = mt*16 + kg*4 + i;
        if (n < NNQ) attn[base + (size_t)n*64 + e] = a2[nt][i]*0.125f;
      }
    }
  }
}

// ---- LIF scan on attention out -> bf16 spikes [tt,(b,n),C] ----
__global__ void k_lif_attn(const float* __restrict__ ain, const float* __restrict__ w,
                           float* __restrict__ vo, u16* __restrict__ sp, int t0, int tc){
  int g = blockIdx.x*256 + threadIdx.x;
  int e = g & 63;
  int n = (g>>6) % NNQ;
  int h = (g/(NNQ*64)) & 7;
  int b = g/(NNQ*64*8);
  size_t dst = (size_t)(b*NNQ + n)*CC + h*HD + e;
  float sg = sigm(w[0]);
  float v = (t0==0) ? 0.f : vo[g];
  for (int tt=0; tt<tc; ++tt){
    float s = lif_step(ain[(size_t)tt*PT + g], v, sg);
    sp[(size_t)tt*PT + dst] = (s!=0.f) ? 0x3F80 : 0;
  }
  vo[g] = v;
}

// ---- BN2 fused stats(fp64)+apply ----
__global__ void k_bn2(const float* __restrict__ X, const float* __restrict__ g2,
                      const float* __restrict__ b2, float* __restrict__ Y, int t0){
  int c = blockIdx.x*64 + threadIdx.x;
  int tt = blockIdx.y;
  const float* Xb = X + (size_t)tt*(size_t)BN*CC;
  float* Yb = Y + (size_t)(t0+tt)*PT;
  double sum=0.0, sq=0.0;
  for (int i=threadIdx.y; i<BN; i+=4){
    double v = (double)Xb[(size_t)i*CC + c];
    sum += v; sq += v*v;
  }
  __shared__ double ssum[4][64], ssq[4][64];
  ssum[threadIdx.y][threadIdx.x]=sum;
  ssq [threadIdx.y][threadIdx.x]=sq;
  __syncthreads();
  double s = ssum[0][threadIdx.x]+ssum[1][threadIdx.x]+ssum[2][threadIdx.x]+ssum[3][threadIdx.x];
  double q = ssq [0][threadIdx.x]+ssq [1][threadIdx.x]+ssq [2][threadIdx.x]+ssq [3][threadIdx.x];
  double m = s*(1.0/BN);
  double var = q*(1.0/BN) - m*m;
  float mf = (float)m;
  float rs = (float)(1.0/sqrt(var+1e-5));
  float gg = g2[(t0+tt)*CC+c];
  float bb = b2[(t0+tt)*CC+c];
  for (int i=threadIdx.y; i<BN; i+=4){
    float xv = Xb[(size_t)i*CC + c];
    Yb[(size_t)i*CC + c] =
      __fadd_rn(__fmul_rn(__fmul_rn(__fsub_rn(xv, mf), rs), gg), bb);
  }
}

extern "C" void kernel_launch(void* const* d_in, const int* in_sizes, int n_in,
                              void* d_out, int out_size, void* d_ws, size_t ws_size,
                              hipStream_t stream){
  const float* x      = (const float*)d_in[0];
  const float* qkv_w  = (const float*)d_in[1];
  const float* qkv_b  = (const float*)d_in[2];
  const float* bn1_g  = (const float*)d_in[3];
  const float* bn1_b  = (const float*)d_in[4];
  const float* proj_w = (const float*)d_in[5];
  const float* proj_b = (const float*)d_in[6];
  const float* bn2_g  = (const float*)d_in[7];
  const float* bn2_b  = (const float*)d_in[8];
  const float* w_in   = (const float*)d_in[9];
  const float* w_q    = (const float*)d_in[10];
  const float* w_k    = (const float*)d_in[11];
  const float* w_v    = (const float*)d_in[12];
  const float* w_proj = (const float*)d_in[13];
  float* outp = (float*)d_out;

  // need(tc) = states + stats + splitw + spikes + R(qkv_all)
  auto need = [](int tc)->size_t{
    return 4ull*5*PT + 8ull*tc*O3 + 6ull*WTOT
         + 10ull*tc*PT            // 5 bf16 spike bufs
         + 4ull*tc*BN*O3;         // R region (qkv_all; attn+projo overlap)
  };
  int TC = 16;
  while (TC > 1 && need(TC) > ws_size) TC >>= 1;

  char* p = (char*)d_ws;
  float* vin = (float*)p; p += 4ull*PT;
  float* vq  = (float*)p; p += 4ull*PT;
  float* vk  = (float*)p; p += 4ull*PT;
  float* vv  = (float*)p; p += 4ull*PT;
  float* vo  = (float*)p; p += 4ull*PT;
  float* mean1 = (float*)p; p += 4ull*TC*O3;
  float* rstd1 = (float*)p; p += 4ull*TC*O3;
  u16* whi  = (u16*)p; p += 2ull*WTOT;
  u16* wmid = (u16*)p; p += 2ull*WTOT;
  u16* wlo  = (u16*)p; p += 2ull*WTOT;
  u16* s0    = (u16*)p; p += 2ull*TC*PT;
  u16* qsb   = (u16*)p; p += 2ull*TC*PT;
  u16* ksb   = (u16*)p; p += 2ull*TC*PT;
  u16* vsb   = (u16*)p; p += 2ull*TC*PT;
  u16* sproj = (u16*)p; p += 2ull*TC*PT;
  float* qkv_all = (float*)p;                 // tc*BN*O3 floats
  float* attn    = qkv_all;                   // tc*PT (overlaps dead qkv_all)
  float* projo   = qkv_all + (size_t)TC*PT;   // tc*PT

  k_wsplit<<<WTOT/256, 256, 0, stream>>>(qkv_w, proj_w, whi, wmid, wlo);

  for (int t0=0; t0<TT; t0+=TC){
    int M = TC*BN;
    k_lif_x<<<PT/256, 256, 0, stream>>>(x, w_in, vin, s0, t0, TC);

    k_gemm_mfma<O3><<<dim3((M+127)/128, O3/128), 256, 0, stream>>>(
        s0, whi, wmid, wlo, qkv_b, qkv_all, M);

    k_bn1_stats<<<dim3(O3/64, TC), dim3(64,4), 0, stream>>>(qkv_all, mean1, rstd1);

    k_lif_qkv<<<dim3(PT/256, 3), 256, 0, stream>>>(qkv_all, mean1, rstd1, bn1_g, bn1_b,
                                                   w_q, w_k, w_v, vq, vk, vv,
                                                   qsb, ksb, vsb, t0, TC);

    k_kvqv_mfma<<<TC*BB*HH, 256, 0, stream>>>(ksb, vsb, qsb, attn);

    k_lif_attn<<<PT/256, 256, 0, stream>>>(attn, w_proj, vo, sproj, t0, TC);

    k_gemm_mfma<CC><<<dim3((M+127)/128, CC/128), 256, 0, stream>>>(
        sproj, whi + (size_t)O3*CC, wmid + (size_t)O3*CC, wlo + (size_t)O3*CC,
        proj_b, projo, M);

    k_bn2<<<dim3(CC/64, TC), dim3(64,4), 0, stream>>>(projo, bn2_g, bn2_b, outp, t0);
  }
}

// Round 6
// 465.784 us; speedup vs baseline: 31.2916x; 1.9182x over previous
//
#include <hip/hip_runtime.h>

// Spiking self-attention (Spikformer SSA) forward — MFMA GEMM/attention,
// grid-saturating 3-stage BN. Spikes/kv exact in bf16; weights 3-way bf16
// split. T-chunked by ws_size. T=16,B=8,N=196,C=512,H=8,hd=64.

#define TT 16
#define BB 8
#define NNQ 196
#define CC 512
#define HH 8
#define HD 64
#define O3 1536
#define BN (BB*NNQ)          // 1568
#define PT (BN*CC)           // 802816
#define WTOT ((O3+CC)*CC)    // 1048576 split-weight elems
#define NRG 14               // row-groups for BN stats (1568 = 14*112)

static constexpr float VTH = 0.5f;
typedef __attribute__((ext_vector_type(8))) short short8;
typedef __attribute__((ext_vector_type(4))) float f32x4;
typedef unsigned short u16;

__device__ __forceinline__ float sigm(float w){ return 1.f/(1.f+expf(-w)); }

__device__ __forceinline__ float lif_step(float x, float& v, float sg){
  float d  = __fsub_rn(x, v);
  float dd = __fmul_rn(d, sg);
  v = __fadd_rn(v, dd);
  float sp = (v >= VTH) ? 1.f : 0.f;
  v = __fmul_rn(v, __fsub_rn(1.f, sp));
  return sp;
}

__device__ __forceinline__ u16 bf16_rn(float x){
  unsigned u = __float_as_uint(x);
  unsigned r = u + 0x7FFF + ((u>>16)&1);
  return (u16)(r>>16);
}
__device__ __forceinline__ float bf16_to_f(u16 h){
  return __uint_as_float(((unsigned)h)<<16);
}

// ---- split weights into hi/mid/lo bf16 ----
__global__ void k_wsplit(const float* __restrict__ qkv_w, const float* __restrict__ proj_w,
                         u16* __restrict__ whi, u16* __restrict__ wmid, u16* __restrict__ wlo){
  int i = blockIdx.x*256 + threadIdx.x;
  float w = (i < O3*CC) ? qkv_w[i] : proj_w[i - O3*CC];
  u16 h = bf16_rn(w);          float r1 = w - bf16_to_f(h);
  u16 m = bf16_rn(r1);         float r2 = r1 - bf16_to_f(m);
  u16 l = bf16_rn(r2);
  whi[i]=h; wmid[i]=m; wlo[i]=l;
}

// ---- LIF scan on input x -> bf16 spikes ----
__global__ void k_lif_x(const float* __restrict__ x, const float* __restrict__ w,
                        float* __restrict__ vin, u16* __restrict__ s0, int t0, int tc){
  int g = blockIdx.x*256 + threadIdx.x;
  float sg = sigm(w[0]);
  float v = (t0==0) ? 0.f : vin[g];
  for (int tt=0; tt<tc; ++tt){
    float sp = lif_step(x[(size_t)(t0+tt)*PT + g], v, sg);
    s0[(size_t)tt*PT + g] = (sp!=0.f) ? 0x3F80 : 0;
  }
  vin[g] = v;
}

// ---- C[M,ON] = A(bf16 0/1)[M,512] * (Whi+Wmid+Wlo)[ON,512]^T + bias ----
template<int ON>
__global__ __launch_bounds__(256)
void k_gemm_mfma(const u16* __restrict__ A, const u16* __restrict__ Wh,
                 const u16* __restrict__ Wm, const u16* __restrict__ Wl,
                 const float* __restrict__ bias, float* __restrict__ Cm, int M){
  __shared__ __align__(16) u16 Al[128][64];
  __shared__ __align__(16) u16 Bh[128][64];
  __shared__ __align__(16) u16 Bm[128][64];
  __shared__ __align__(16) u16 Bl[128][64];
  int tid = threadIdx.x;
  int w = tid>>6, lane = tid&63;
  int m0 = blockIdx.x*128, o0 = blockIdx.y*128;
  int wm = (w&1)*64, wn = (w>>1)*64;
  int r16 = lane&15, kg = lane>>4;
  f32x4 acc[4][4] = {};
  for (int k0=0;k0<512;k0+=64){
    #pragma unroll
    for (int i=0;i<4;++i){
      int u = tid*4 + i;            // 0..1023
      int row = u>>3, slot = u&7;
      int sl = slot ^ (row&7);
      int gr = m0+row; if (gr>=M) gr=M-1;
      *(float4*)&Al[row][sl*8] = *(const float4*)&A [(size_t)gr*512      + k0 + slot*8];
      *(float4*)&Bh[row][sl*8] = *(const float4*)&Wh[(size_t)(o0+row)*512 + k0 + slot*8];
      *(float4*)&Bm[row][sl*8] = *(const float4*)&Wm[(size_t)(o0+row)*512 + k0 + slot*8];
      *(float4*)&Bl[row][sl*8] = *(const float4*)&Wl[(size_t)(o0+row)*512 + k0 + slot*8];
    }
    __syncthreads();
    #pragma unroll
    for (int s=0;s<2;++s){
      short8 af[4], bh[4], bm[4], bl[4];
      #pragma unroll
      for (int mt=0;mt<4;++mt){
        int r = wm + mt*16 + r16;
        af[mt] = *(const short8*)&Al[r][((s*4+kg)^(r&7))*8];
      }
      #pragma unroll
      for (int nt=0;nt<4;++nt){
        int r = wn + nt*16 + r16;
        int sl = ((s*4+kg)^(r&7))*8;
        bh[nt] = *(const short8*)&Bh[r][sl];
        bm[nt] = *(const short8*)&Bm[r][sl];
        bl[nt] = *(const short8*)&Bl[r][sl];
      }
      #pragma unroll
      for (int mt=0;mt<4;++mt)
        #pragma unroll
        for (int nt=0;nt<4;++nt){
          acc[mt][nt] = __builtin_amdgcn_mfma_f32_16x16x32_bf16(af[mt], bh[nt], acc[mt][nt],0,0,0);
          acc[mt][nt] = __builtin_amdgcn_mfma_f32_16x16x32_bf16(af[mt], bm[nt], acc[mt][nt],0,0,0);
          acc[mt][nt] = __builtin_amdgcn_mfma_f32_16x16x32_bf16(af[mt], bl[nt], acc[mt][nt],0,0,0);
        }
    }
    __syncthreads();
  }
  #pragma unroll
  for (int mt=0; mt<4; ++mt)
    #pragma unroll
    for (int nt=0; nt<4; ++nt){
      int o = o0 + wn + nt*16 + r16;
      float bs = bias[o];
      #pragma unroll
      for (int i=0;i<4;++i){
        int m = m0 + wm + mt*16 + kg*4 + i;
        if (m < M) Cm[(size_t)m*ON + o] = acc[mt][nt][i] + bs;
      }
    }
}

// ---- BN stats stage 1: fp64 partials over 112-row groups ----
template<int O>
__global__ void k_stat_part(const float* __restrict__ X, double* __restrict__ psum,
                            double* __restrict__ psq){
  int o = blockIdx.x*64 + threadIdx.x;
  int tt = blockIdx.y;
  int rg = blockIdx.z;
  const float* Xb = X + (size_t)tt*BN*O;
  int r0 = rg*112;
  double sum=0.0, sq=0.0;
  for (int i=r0+threadIdx.y; i<r0+112; i+=4){
    double v = (double)Xb[(size_t)i*O + o];
    sum += v; sq += v*v;
  }
  __shared__ double ssum[4][64], ssq[4][64];
  ssum[threadIdx.y][threadIdx.x]=sum;
  ssq [threadIdx.y][threadIdx.x]=sq;
  __syncthreads();
  if (threadIdx.y==0){
    double s = ssum[0][threadIdx.x]+ssum[1][threadIdx.x]+ssum[2][threadIdx.x]+ssum[3][threadIdx.x];
    double q = ssq [0][threadIdx.x]+ssq [1][threadIdx.x]+ssq [2][threadIdx.x]+ssq [3][threadIdx.x];
    size_t idx = ((size_t)tt*O + o)*NRG + rg;
    psum[idx]=s; psq[idx]=q;
  }
}

// ---- BN stats stage 2: fold partials -> mean/rstd ----
template<int O, int TCN>
__global__ void k_stat_reduce(const double* __restrict__ psum, const double* __restrict__ psq,
                              float* __restrict__ mean, float* __restrict__ rstd){
  int i = blockIdx.x*256 + threadIdx.x;   // tt*O + o
  if (i >= TCN*O) return;
  double s=0.0, q=0.0;
  #pragma unroll
  for (int g=0; g<NRG; ++g){ s += psum[(size_t)i*NRG+g]; q += psq[(size_t)i*NRG+g]; }
  double m = s*(1.0/BN);
  double var = q*(1.0/BN) - m*m;
  mean[i]=(float)m;
  rstd[i]=(float)(1.0/sqrt(var+1e-5));
}

// ---- BN1 + LIF scan q/k/v -> bf16 spikes [tt,b,h,n,d] ----
__global__ void k_lif_qkv(const float* __restrict__ qkv, const float* __restrict__ mean,
                          const float* __restrict__ rstd, const float* __restrict__ g1,
                          const float* __restrict__ b1,
                          const float* __restrict__ wq, const float* __restrict__ wk,
                          const float* __restrict__ wv,
                          float* __restrict__ vq, float* __restrict__ vk, float* __restrict__ vv,
                          u16* __restrict__ qs, u16* __restrict__ ks,
                          u16* __restrict__ vs, int t0, int tc){
  int g = blockIdx.x*256 + threadIdx.x;
  int j = blockIdx.y;
  int d = g & 63;
  int n = (g>>6) % NNQ;
  int h = (g/(NNQ*64)) & 7;
  int b = g/(NNQ*64*8);
  int o = j*CC + h*HD + d;
  const float* w = (j==0)? wq : (j==1)? wk : wv;
  float* st  = (j==0)? vq : (j==1)? vk : vv;
  u16* out = (j==0)? qs : (j==1)? ks : vs;
  float sg = sigm(w[0]);
  float v = (t0==0) ? 0.f : st[g];
  size_t row = (size_t)(b*NNQ + n)*O3 + o;
  for (int tt=0; tt<tc; ++tt){
    float xv = qkv[(size_t)tt*BN*O3 + row];
    int so = tt*O3 + o;
    int go = (t0+tt)*O3 + o;
    float xn = __fadd_rn(__fmul_rn(__fmul_rn(__fsub_rn(xv, mean[so]), rstd[so]),
                                   g1[go]), b1[go]);
    float sp = lif_step(xn, v, sg);
    out[(size_t)tt*PT + g] = (sp!=0.f) ? 0x3F80 : 0;
  }
  st[g] = v;
}

// ---- per (tt,b,h): kv = K^T V (MFMA), then attn = 0.125 * Q kv (MFMA) ----
__global__ __launch_bounds__(256)
void k_kvqv_mfma(const u16* __restrict__ ks, const u16* __restrict__ vs,
                 const u16* __restrict__ qs, float* __restrict__ attn){
  __shared__ __align__(16) u16 Kb[224][64];
  __shared__ __align__(16) u16 Vb[224][64];
  __shared__ __align__(16) u16 kvb[64][64];
  int blk = blockIdx.x;
  size_t base = (size_t)blk * (NNQ*HD);
  int tid = threadIdx.x, w = tid>>6, lane = tid&63;
  int r16 = lane&15, kg = lane>>4;
  for (int u=tid; u<224*8; u+=256){
    int row=u>>3, slot=u&7;
    float4 z = {0.f,0.f,0.f,0.f};
    float4 kd = z, vd = z;
    if (row < NNQ){
      kd = *(const float4*)&ks[base + (size_t)row*64 + slot*8];
      vd = *(const float4*)&vs[base + (size_t)row*64 + slot*8];
    }
    *(float4*)&Kb[row][slot*8] = kd;
    *(float4*)&Vb[row][slot*8] = vd;
  }
  __syncthreads();
  f32x4 acc[4] = {};
  int d0 = w*16;
  for (int n0=0;n0<224;n0+=32){
    short8 af;
    #pragma unroll
    for (int jj=0;jj<8;++jj) af[jj] = (short)Kb[n0+kg*8+jj][d0 + r16];
    #pragma unroll
    for (int nt=0;nt<4;++nt){
      short8 bf;
      #pragma unroll
      for (int jj=0;jj<8;++jj) bf[jj] = (short)Vb[n0+kg*8+jj][nt*16 + r16];
      acc[nt] = __builtin_amdgcn_mfma_f32_16x16x32_bf16(af, bf, acc[nt],0,0,0);
    }
  }
  #pragma unroll
  for (int nt=0;nt<4;++nt)
    #pragma unroll
    for (int i=0;i<4;++i)
      kvb[d0 + kg*4 + i][nt*16 + r16] = (u16)(__float_as_uint(acc[nt][i])>>16);
  __syncthreads();
  for (int u=tid; u<224*8; u+=256){
    int row=u>>3, slot=u&7;
    int sl = slot ^ (row&7);
    float4 qd = {0.f,0.f,0.f,0.f};
    if (row < NNQ) qd = *(const float4*)&qs[base + (size_t)row*64 + slot*8];
    *(float4*)&Kb[row][sl*8] = qd;
  }
  __syncthreads();
  short8 bkv[2][4];
  #pragma unroll
  for (int s=0;s<2;++s)
    #pragma unroll
    for (int nt=0;nt<4;++nt){
      short8 bf;
      #pragma unroll
      for (int jj=0;jj<8;++jj) bf[jj] = (short)kvb[s*32 + kg*8 + jj][nt*16 + r16];
      bkv[s][nt] = bf;
    }
  for (int mt=w; mt<13; mt+=4){
    f32x4 a2[4] = {};
    short8 qa[2];
    #pragma unroll
    for (int s=0;s<2;++s){
      int r = mt*16 + r16;
      qa[s] = *(const short8*)&Kb[r][(((s*4+kg)^(r&7)))*8];
    }
    #pragma unroll
    for (int s=0;s<2;++s)
      #pragma unroll
      for (int nt=0;nt<4;++nt)
        a2[nt] = __builtin_amdgcn_mfma_f32_16x16x32_bf16(qa[s], bkv[s][nt], a2[nt],0,0,0);
    #pragma unroll
    for (int nt=0;nt<4;++nt){
      int e = nt*16 + r16;
      #pragma unroll
      for (int i=0;i<4;++i){
        int n = mt*16 + kg*4 + i;
        if (n < NNQ) attn[base + (size_t)n*64 + e] = a2[nt][i]*0.125f;
      }
    }
  }
}

// ---- LIF scan on attention out -> bf16 spikes [tt,(b,n),C] ----
__global__ void k_lif_attn(const float* __restrict__ ain, const float* __restrict__ w,
                           float* __restrict__ vo, u16* __restrict__ sp, int t0, int tc){
  int g = blockIdx.x*256 + threadIdx.x;
  int e = g & 63;
  int n = (g>>6) % NNQ;
  int h = (g/(NNQ*64)) & 7;
  int b = g/(NNQ*64*8);
  size_t dst = (size_t)(b*NNQ + n)*CC + h*HD + e;
  float sg = sigm(w[0]);
  float v = (t0==0) ? 0.f : vo[g];
  for (int tt=0; tt<tc; ++tt){
    float s = lif_step(ain[(size_t)tt*PT + g], v, sg);
    sp[(size_t)tt*PT + dst] = (s!=0.f) ? 0x3F80 : 0;
  }
  vo[g] = v;
}

// ---- BN2 apply (vectorized, np-rounded): Y[(t0+tt),i,c] from X[tt,i,c] ----
__global__ void k_bn2_apply(const float* __restrict__ X, const float* __restrict__ mean,
                            const float* __restrict__ rstd, const float* __restrict__ g2,
                            const float* __restrict__ b2, float* __restrict__ Y, int t0){
  size_t idx = ((size_t)blockIdx.x*256 + threadIdx.x)*4;
  int tt = (int)(idx / PT);
  size_t off = idx - (size_t)tt*PT;
  int c = (int)(off & (CC-1));
  float4 xv = *(const float4*)&X[idx];
  float4 mv = *(const float4*)&mean[tt*CC + c];
  float4 rv = *(const float4*)&rstd[tt*CC + c];
  float4 gv = *(const float4*)&g2[(t0+tt)*CC + c];
  float4 bv = *(const float4*)&b2[(t0+tt)*CC + c];
  float4 yv;
  yv.x = __fadd_rn(__fmul_rn(__fmul_rn(__fsub_rn(xv.x, mv.x), rv.x), gv.x), bv.x);
  yv.y = __fadd_rn(__fmul_rn(__fmul_rn(__fsub_rn(xv.y, mv.y), rv.y), gv.y), bv.y);
  yv.z = __fadd_rn(__fmul_rn(__fmul_rn(__fsub_rn(xv.z, mv.z), rv.z), gv.z), bv.z);
  yv.w = __fadd_rn(__fmul_rn(__fmul_rn(__fsub_rn(xv.w, mv.w), rv.w), gv.w), bv.w);
  *(float4*)&Y[(size_t)(t0+tt)*PT + off] = yv;
}

extern "C" void kernel_launch(void* const* d_in, const int* in_sizes, int n_in,
                              void* d_out, int out_size, void* d_ws, size_t ws_size,
                              hipStream_t stream){
  const float* x      = (const float*)d_in[0];
  const float* qkv_w  = (const float*)d_in[1];
  const float* qkv_b  = (const float*)d_in[2];
  const float* bn1_g  = (const float*)d_in[3];
  const float* bn1_b  = (const float*)d_in[4];
  const float* proj_w = (const float*)d_in[5];
  const float* proj_b = (const float*)d_in[6];
  const float* bn2_g  = (const float*)d_in[7];
  const float* bn2_b  = (const float*)d_in[8];
  const float* w_in   = (const float*)d_in[9];
  const float* w_q    = (const float*)d_in[10];
  const float* w_k    = (const float*)d_in[11];
  const float* w_v    = (const float*)d_in[12];
  const float* w_proj = (const float*)d_in[13];
  float* outp = (float*)d_out;

  auto need = [](int tc)->size_t{
    return 4ull*5*PT + 8ull*tc*O3 + 8ull*tc*CC
         + 16ull*tc*O3*NRG + 16ull*tc*CC*NRG
         + 6ull*WTOT
         + 10ull*tc*PT
         + 4ull*tc*BN*O3;
  };
  int TC = 16;
  while (TC > 1 && need(TC) > ws_size) TC >>= 1;

  char* p = (char*)d_ws;
  float* vin = (float*)p; p += 4ull*PT;
  float* vq  = (float*)p; p += 4ull*PT;
  float* vk  = (float*)p; p += 4ull*PT;
  float* vv  = (float*)p; p += 4ull*PT;
  float* vo  = (float*)p; p += 4ull*PT;
  float* mean1 = (float*)p; p += 4ull*TC*O3;
  float* rstd1 = (float*)p; p += 4ull*TC*O3;
  float* mean2 = (float*)p; p += 4ull*TC*CC;
  float* rstd2 = (float*)p; p += 4ull*TC*CC;
  double* p1sum = (double*)p; p += 8ull*TC*O3*NRG;
  double* p1sq  = (double*)p; p += 8ull*TC*O3*NRG;
  double* p2sum = (double*)p; p += 8ull*TC*CC*NRG;
  double* p2sq  = (double*)p; p += 8ull*TC*CC*NRG;
  u16* whi  = (u16*)p; p += 2ull*WTOT;
  u16* wmid = (u16*)p; p += 2ull*WTOT;
  u16* wlo  = (u16*)p; p += 2ull*WTOT;
  u16* s0    = (u16*)p; p += 2ull*TC*PT;
  u16* qsb   = (u16*)p; p += 2ull*TC*PT;
  u16* ksb   = (u16*)p; p += 2ull*TC*PT;
  u16* vsb   = (u16*)p; p += 2ull*TC*PT;
  u16* sproj = (u16*)p; p += 2ull*TC*PT;
  float* qkv_all = (float*)p;                 // tc*BN*O3 floats
  float* attn    = qkv_all;                   // tc*PT (overlaps dead qkv_all)
  float* projo   = qkv_all + (size_t)TC*PT;   // tc*PT

  k_wsplit<<<WTOT/256, 256, 0, stream>>>(qkv_w, proj_w, whi, wmid, wlo);

  for (int t0=0; t0<TT; t0+=TC){
    int M = TC*BN;
    k_lif_x<<<PT/256, 256, 0, stream>>>(x, w_in, vin, s0, t0, TC);

    k_gemm_mfma<O3><<<dim3((M+127)/128, O3/128), 256, 0, stream>>>(
        s0, whi, wmid, wlo, qkv_b, qkv_all, M);

    k_stat_part<O3><<<dim3(O3/64, TC, NRG), dim3(64,4), 0, stream>>>(qkv_all, p1sum, p1sq);
    if (TC == 16)
      k_stat_reduce<O3,16><<<(16*O3+255)/256, 256, 0, stream>>>(p1sum, p1sq, mean1, rstd1);
    else if (TC == 8)
      k_stat_reduce<O3,8><<<(8*O3+255)/256, 256, 0, stream>>>(p1sum, p1sq, mean1, rstd1);
    else
      k_stat_reduce<O3,4><<<(4*O3+255)/256, 256, 0, stream>>>(p1sum, p1sq, mean1, rstd1);

    k_lif_qkv<<<dim3(PT/256, 3), 256, 0, stream>>>(qkv_all, mean1, rstd1, bn1_g, bn1_b,
                                                   w_q, w_k, w_v, vq, vk, vv,
                                                   qsb, ksb, vsb, t0, TC);

    k_kvqv_mfma<<<TC*BB*HH, 256, 0, stream>>>(ksb, vsb, qsb, attn);

    k_lif_attn<<<PT/256, 256, 0, stream>>>(attn, w_proj, vo, sproj, t0, TC);

    k_gemm_mfma<CC><<<dim3((M+127)/128, CC/128), 256, 0, stream>>>(
        sproj, whi + (size_t)O3*CC, wmid + (size_t)O3*CC, wlo + (size_t)O3*CC,
        proj_b, projo, M);

    k_stat_part<CC><<<dim3(CC/64, TC, NRG), dim3(64,4), 0, stream>>>(projo, p2sum, p2sq);
    if (TC == 16)
      k_stat_reduce<CC,16><<<(16*CC+255)/256, 256, 0, stream>>>(p2sum, p2sq, mean2, rstd2);
    else if (TC == 8)
      k_stat_reduce<CC,8><<<(8*CC+255)/256, 256, 0, stream>>>(p2sum, p2sq, mean2, rstd2);
    else
      k_stat_reduce<CC,4><<<(4*CC+255)/256, 256, 0, stream>>>(p2sum, p2sq, mean2, rstd2);

    k_bn2_apply<<<(TC*(size_t)PT)/1024, 256, 0, stream>>>(projo, mean2, rstd2,
                                                          bn2_g, bn2_b, outp, t0);
  }
}

// Round 7
// 410.928 us; speedup vs baseline: 35.4688x; 1.1335x over previous
//
#include <hip/hip_runtime.h>

// Spiking self-attention (Spikformer SSA) forward — MFMA GEMM/attention,
// grid-saturating 3-stage BN. GEMM: global_load_lds staging (pre-swizzled
// source) + bijective XCD-chunked grid swizzle. T=16,B=8,N=196,C=512,H=8,hd=64.

#define TT 16
#define BB 8
#define NNQ 196
#define CC 512
#define HH 8
#define HD 64
#define O3 1536
#define BN (BB*NNQ)          // 1568
#define PT (BN*CC)           // 802816
#define WTOT ((O3+CC)*CC)    // 1048576 split-weight elems
#define NRG 14               // row-groups for BN stats (1568 = 14*112)

static constexpr float VTH = 0.5f;
typedef __attribute__((ext_vector_type(8))) short short8;
typedef __attribute__((ext_vector_type(4))) float f32x4;
typedef unsigned short u16;

__device__ __forceinline__ float sigm(float w){ return 1.f/(1.f+expf(-w)); }

__device__ __forceinline__ float lif_step(float x, float& v, float sg){
  float d  = __fsub_rn(x, v);
  float dd = __fmul_rn(d, sg);
  v = __fadd_rn(v, dd);
  float sp = (v >= VTH) ? 1.f : 0.f;
  v = __fmul_rn(v, __fsub_rn(1.f, sp));
  return sp;
}

__device__ __forceinline__ u16 bf16_rn(float x){
  unsigned u = __float_as_uint(x);
  unsigned r = u + 0x7FFF + ((u>>16)&1);
  return (u16)(r>>16);
}
__device__ __forceinline__ float bf16_to_f(u16 h){
  return __uint_as_float(((unsigned)h)<<16);
}

// async global->LDS, 16B per lane; LDS dest = wave-uniform base + lane*16
__device__ __forceinline__ void gld_lds16(const void* g, void* l){
  __builtin_amdgcn_global_load_lds(
    (const __attribute__((address_space(1))) unsigned int*)g,
    (__attribute__((address_space(3))) unsigned int*)l, 16, 0, 0);
}

// ---- split weights into hi/mid/lo bf16 ----
__global__ void k_wsplit(const float* __restrict__ qkv_w, const float* __restrict__ proj_w,
                         u16* __restrict__ whi, u16* __restrict__ wmid, u16* __restrict__ wlo){
  int i = blockIdx.x*256 + threadIdx.x;
  float w = (i < O3*CC) ? qkv_w[i] : proj_w[i - O3*CC];
  u16 h = bf16_rn(w);          float r1 = w - bf16_to_f(h);
  u16 m = bf16_rn(r1);         float r2 = r1 - bf16_to_f(m);
  u16 l = bf16_rn(r2);
  whi[i]=h; wmid[i]=m; wlo[i]=l;
}

// ---- LIF scan on input x -> bf16 spikes ----
__global__ void k_lif_x(const float* __restrict__ x, const float* __restrict__ w,
                        float* __restrict__ vin, u16* __restrict__ s0, int t0, int tc){
  int g = blockIdx.x*256 + threadIdx.x;
  float sg = sigm(w[0]);
  float v = (t0==0) ? 0.f : vin[g];
  for (int tt=0; tt<tc; ++tt){
    float sp = lif_step(x[(size_t)(t0+tt)*PT + g], v, sg);
    s0[(size_t)tt*PT + g] = (sp!=0.f) ? 0x3F80 : 0;
  }
  vin[g] = v;
}

// ---- C[M,ON] = A(bf16 0/1)[M,512] * (Whi+Wmid+Wlo)[ON,512]^T + bias ----
template<int ON>
__global__ __launch_bounds__(256)
void k_gemm_mfma(const u16* __restrict__ A, const u16* __restrict__ Wh,
                 const u16* __restrict__ Wm, const u16* __restrict__ Wl,
                 const float* __restrict__ bias, float* __restrict__ Cm, int M){
  __shared__ __align__(16) u16 Al[128][64];
  __shared__ __align__(16) u16 Bh[128][64];
  __shared__ __align__(16) u16 Bm[128][64];
  __shared__ __align__(16) u16 Bl[128][64];
  // 1D grid, bijective XCD-chunked swizzle (m204): chunk shares A-panel slice
  const int nON = ON/128;
  int nwg = gridDim.x;
  int bid = blockIdx.x;
  int q = nwg >> 3, r = nwg & 7;
  int xcd = bid & 7, idx = bid >> 3;
  int wgid = (xcd < r ? xcd*(q+1) : r*(q+1) + (xcd-r)*q) + idx;
  int mb = wgid / nON, ob = wgid - mb*nON;
  int m0 = mb*128, o0 = ob*128;

  int tid = threadIdx.x;
  int w = tid>>6, lane = tid&63;
  int wm = (w&1)*64, wn = (w>>1)*64;
  int r16 = lane&15, kg = lane>>4;
  int lrow = w*32 + (lane>>3);       // staging row (this wave covers 32 rows/buf)
  int lslot = lane&7;
  f32x4 acc[4][4] = {};
  for (int k0=0;k0<512;k0+=64){
    #pragma unroll
    for (int i=0;i<4;++i){
      int row = lrow + i*8;                 // row within 128-tile (uniform per i)
      int gslot = lslot ^ (row&7);          // pre-swizzled global source slot
      int gr = m0+row; if (gr>=M) gr=M-1;
      gld_lds16(&A [(size_t)gr*512       + k0 + gslot*8], &Al[w*32+i*8][0]);
      gld_lds16(&Wh[(size_t)(o0+row)*512 + k0 + gslot*8], &Bh[w*32+i*8][0]);
      gld_lds16(&Wm[(size_t)(o0+row)*512 + k0 + gslot*8], &Bm[w*32+i*8][0]);
      gld_lds16(&Wl[(size_t)(o0+row)*512 + k0 + gslot*8], &Bl[w*32+i*8][0]);
    }
    __syncthreads();
    #pragma unroll
    for (int s=0;s<2;++s){
      short8 af[4], bh[4], bm[4], bl[4];
      #pragma unroll
      for (int mt=0;mt<4;++mt){
        int rr = wm + mt*16 + r16;
        af[mt] = *(const short8*)&Al[rr][((s*4+kg)^(rr&7))*8];
      }
      #pragma unroll
      for (int nt=0;nt<4;++nt){
        int rr = wn + nt*16 + r16;
        int sl = ((s*4+kg)^(rr&7))*8;
        bh[nt] = *(const short8*)&Bh[rr][sl];
        bm[nt] = *(const short8*)&Bm[rr][sl];
        bl[nt] = *(const short8*)&Bl[rr][sl];
      }
      #pragma unroll
      for (int mt=0;mt<4;++mt)
        #pragma unroll
        for (int nt=0;nt<4;++nt){
          acc[mt][nt] = __builtin_amdgcn_mfma_f32_16x16x32_bf16(af[mt], bh[nt], acc[mt][nt],0,0,0);
          acc[mt][nt] = __builtin_amdgcn_mfma_f32_16x16x32_bf16(af[mt], bm[nt], acc[mt][nt],0,0,0);
          acc[mt][nt] = __builtin_amdgcn_mfma_f32_16x16x32_bf16(af[mt], bl[nt], acc[mt][nt],0,0,0);
        }
    }
    __syncthreads();
  }
  #pragma unroll
  for (int mt=0; mt<4; ++mt)
    #pragma unroll
    for (int nt=0; nt<4; ++nt){
      int o = o0 + wn + nt*16 + r16;
      float bs = bias[o];
      #pragma unroll
      for (int i=0;i<4;++i){
        int m = m0 + wm + mt*16 + kg*4 + i;
        if (m < M) Cm[(size_t)m*ON + o] = acc[mt][nt][i] + bs;
      }
    }
}

// ---- BN stats stage 1: fp64 partials over 112-row groups ----
template<int O>
__global__ void k_stat_part(const float* __restrict__ X, double* __restrict__ psum,
                            double* __restrict__ psq){
  int o = blockIdx.x*64 + threadIdx.x;
  int tt = blockIdx.y;
  int rg = blockIdx.z;
  const float* Xb = X + (size_t)tt*BN*O;
  int r0 = rg*112;
  double sum=0.0, sq=0.0;
  for (int i=r0+threadIdx.y; i<r0+112; i+=4){
    double v = (double)Xb[(size_t)i*O + o];
    sum += v; sq += v*v;
  }
  __shared__ double ssum[4][64], ssq[4][64];
  ssum[threadIdx.y][threadIdx.x]=sum;
  ssq [threadIdx.y][threadIdx.x]=sq;
  __syncthreads();
  if (threadIdx.y==0){
    double s = ssum[0][threadIdx.x]+ssum[1][threadIdx.x]+ssum[2][threadIdx.x]+ssum[3][threadIdx.x];
    double q = ssq [0][threadIdx.x]+ssq [1][threadIdx.x]+ssq [2][threadIdx.x]+ssq [3][threadIdx.x];
    size_t idx = ((size_t)tt*O + o)*NRG + rg;
    psum[idx]=s; psq[idx]=q;
  }
}

// ---- BN stats stage 2: fold partials -> mean/rstd ----
template<int O, int TCN>
__global__ void k_stat_reduce(const double* __restrict__ psum, const double* __restrict__ psq,
                              float* __restrict__ mean, float* __restrict__ rstd){
  int i = blockIdx.x*256 + threadIdx.x;   // tt*O + o
  if (i >= TCN*O) return;
  double s=0.0, q=0.0;
  #pragma unroll
  for (int g=0; g<NRG; ++g){ s += psum[(size_t)i*NRG+g]; q += psq[(size_t)i*NRG+g]; }
  double m = s*(1.0/BN);
  double var = q*(1.0/BN) - m*m;
  mean[i]=(float)m;
  rstd[i]=(float)(1.0/sqrt(var+1e-5));
}

// ---- BN1 + LIF scan q/k/v -> bf16 spikes [tt,b,h,n,d] ----
__global__ void k_lif_qkv(const float* __restrict__ qkv, const float* __restrict__ mean,
                          const float* __restrict__ rstd, const float* __restrict__ g1,
                          const float* __restrict__ b1,
                          const float* __restrict__ wq, const float* __restrict__ wk,
                          const float* __restrict__ wv,
                          float* __restrict__ vq, float* __restrict__ vk, float* __restrict__ vv,
                          u16* __restrict__ qs, u16* __restrict__ ks,
                          u16* __restrict__ vs, int t0, int tc){
  int g = blockIdx.x*256 + threadIdx.x;
  int j = blockIdx.y;
  int d = g & 63;
  int n = (g>>6) % NNQ;
  int h = (g/(NNQ*64)) & 7;
  int b = g/(NNQ*64*8);
  int o = j*CC + h*HD + d;
  const float* w = (j==0)? wq : (j==1)? wk : wv;
  float* st  = (j==0)? vq : (j==1)? vk : vv;
  u16* out = (j==0)? qs : (j==1)? ks : vs;
  float sg = sigm(w[0]);
  float v = (t0==0) ? 0.f : st[g];
  size_t row = (size_t)(b*NNQ + n)*O3 + o;
  for (int tt=0; tt<tc; ++tt){
    float xv = qkv[(size_t)tt*BN*O3 + row];
    int so = tt*O3 + o;
    int go = (t0+tt)*O3 + o;
    float xn = __fadd_rn(__fmul_rn(__fmul_rn(__fsub_rn(xv, mean[so]), rstd[so]),
                                   g1[go]), b1[go]);
    float sp = lif_step(xn, v, sg);
    out[(size_t)tt*PT + g] = (sp!=0.f) ? 0x3F80 : 0;
  }
  st[g] = v;
}

// ---- per (tt,b,h): kv = K^T V (MFMA), then attn = 0.125 * Q kv (MFMA) ----
__global__ __launch_bounds__(256)
void k_kvqv_mfma(const u16* __restrict__ ks, const u16* __restrict__ vs,
                 const u16* __restrict__ qs, float* __restrict__ attn){
  __shared__ __align__(16) u16 Kb[224][64];
  __shared__ __align__(16) u16 Vb[224][64];
  __shared__ __align__(16) u16 kvb[64][64];
  int blk = blockIdx.x;
  size_t base = (size_t)blk * (NNQ*HD);
  int tid = threadIdx.x, w = tid>>6, lane = tid&63;
  int r16 = lane&15, kg = lane>>4;
  for (int u=tid; u<224*8; u+=256){
    int row=u>>3, slot=u&7;
    float4 z = {0.f,0.f,0.f,0.f};
    float4 kd = z, vd = z;
    if (row < NNQ){
      kd = *(const float4*)&ks[base + (size_t)row*64 + slot*8];
      vd = *(const float4*)&vs[base + (size_t)row*64 + slot*8];
    }
    *(float4*)&Kb[row][slot*8] = kd;
    *(float4*)&Vb[row][slot*8] = vd;
  }
  __syncthreads();
  f32x4 acc[4] = {};
  int d0 = w*16;
  for (int n0=0;n0<224;n0+=32){
    short8 af;
    #pragma unroll
    for (int jj=0;jj<8;++jj) af[jj] = (short)Kb[n0+kg*8+jj][d0 + r16];
    #pragma unroll
    for (int nt=0;nt<4;++nt){
      short8 bf;
      #pragma unroll
      for (int jj=0;jj<8;++jj) bf[jj] = (short)Vb[n0+kg*8+jj][nt*16 + r16];
      acc[nt] = __builtin_amdgcn_mfma_f32_16x16x32_bf16(af, bf, acc[nt],0,0,0);
    }
  }
  #pragma unroll
  for (int nt=0;nt<4;++nt)
    #pragma unroll
    for (int i=0;i<4;++i)
      kvb[d0 + kg*4 + i][nt*16 + r16] = (u16)(__float_as_uint(acc[nt][i])>>16);
  __syncthreads();
  for (int u=tid; u<224*8; u+=256){
    int row=u>>3, slot=u&7;
    int sl = slot ^ (row&7);
    float4 qd = {0.f,0.f,0.f,0.f};
    if (row < NNQ) qd = *(const float4*)&qs[base + (size_t)row*64 + slot*8];
    *(float4*)&Kb[row][sl*8] = qd;
  }
  __syncthreads();
  short8 bkv[2][4];
  #pragma unroll
  for (int s=0;s<2;++s)
    #pragma unroll
    for (int nt=0;nt<4;++nt){
      short8 bf;
      #pragma unroll
      for (int jj=0;jj<8;++jj) bf[jj] = (short)kvb[s*32 + kg*8 + jj][nt*16 + r16];
      bkv[s][nt] = bf;
    }
  for (int mt=w; mt<13; mt+=4){
    f32x4 a2[4] = {};
    short8 qa[2];
    #pragma unroll
    for (int s=0;s<2;++s){
      int rr = mt*16 + r16;
      qa[s] = *(const short8*)&Kb[rr][(((s*4+kg)^(rr&7)))*8];
    }
    #pragma unroll
    for (int s=0;s<2;++s)
      #pragma unroll
      for (int nt=0;nt<4;++nt)
        a2[nt] = __builtin_amdgcn_mfma_f32_16x16x32_bf16(qa[s], bkv[s][nt], a2[nt],0,0,0);
    #pragma unroll
    for (int nt=0;nt<4;++nt){
      int e = nt*16 + r16;
      #pragma unroll
      for (int i=0;i<4;++i){
        int n = mt*16 + kg*4 + i;
        if (n < NNQ) attn[base + (size_t)n*64 + e] = a2[nt][i]*0.125f;
      }
    }
  }
}

// ---- LIF scan on attention out -> bf16 spikes [tt,(b,n),C] ----
__global__ void k_lif_attn(const float* __restrict__ ain, const float* __restrict__ w,
                           float* __restrict__ vo, u16* __restrict__ sp, int t0, int tc){
  int g = blockIdx.x*256 + threadIdx.x;
  int e = g & 63;
  int n = (g>>6) % NNQ;
  int h = (g/(NNQ*64)) & 7;
  int b = g/(NNQ*64*8);
  size_t dst = (size_t)(b*NNQ + n)*CC + h*HD + e;
  float sg = sigm(w[0]);
  float v = (t0==0) ? 0.f : vo[g];
  for (int tt=0; tt<tc; ++tt){
    float s = lif_step(ain[(size_t)tt*PT + g], v, sg);
    sp[(size_t)tt*PT + dst] = (s!=0.f) ? 0x3F80 : 0;
  }
  vo[g] = v;
}

// ---- BN2 apply (vectorized, np-rounded) ----
__global__ void k_bn2_apply(const float* __restrict__ X, const float* __restrict__ mean,
                            const float* __restrict__ rstd, const float* __restrict__ g2,
                            const float* __restrict__ b2, float* __restrict__ Y, int t0){
  size_t idx = ((size_t)blockIdx.x*256 + threadIdx.x)*4;
  int tt = (int)(idx / PT);
  size_t off = idx - (size_t)tt*PT;
  int c = (int)(off & (CC-1));
  float4 xv = *(const float4*)&X[idx];
  float4 mv = *(const float4*)&mean[tt*CC + c];
  float4 rv = *(const float4*)&rstd[tt*CC + c];
  float4 gv = *(const float4*)&g2[(t0+tt)*CC + c];
  float4 bv = *(const float4*)&b2[(t0+tt)*CC + c];
  float4 yv;
  yv.x = __fadd_rn(__fmul_rn(__fmul_rn(__fsub_rn(xv.x, mv.x), rv.x), gv.x), bv.x);
  yv.y = __fadd_rn(__fmul_rn(__fmul_rn(__fsub_rn(xv.y, mv.y), rv.y), gv.y), bv.y);
  yv.z = __fadd_rn(__fmul_rn(__fmul_rn(__fsub_rn(xv.z, mv.z), rv.z), gv.z), bv.z);
  yv.w = __fadd_rn(__fmul_rn(__fmul_rn(__fsub_rn(xv.w, mv.w), rv.w), gv.w), bv.w);
  *(float4*)&Y[(size_t)(t0+tt)*PT + off] = yv;
}

extern "C" void kernel_launch(void* const* d_in, const int* in_sizes, int n_in,
                              void* d_out, int out_size, void* d_ws, size_t ws_size,
                              hipStream_t stream){
  const float* x      = (const float*)d_in[0];
  const float* qkv_w  = (const float*)d_in[1];
  const float* qkv_b  = (const float*)d_in[2];
  const float* bn1_g  = (const float*)d_in[3];
  const float* bn1_b  = (const float*)d_in[4];
  const float* proj_w = (const float*)d_in[5];
  const float* proj_b = (const float*)d_in[6];
  const float* bn2_g  = (const float*)d_in[7];
  const float* bn2_b  = (const float*)d_in[8];
  const float* w_in   = (const float*)d_in[9];
  const float* w_q    = (const float*)d_in[10];
  const float* w_k    = (const float*)d_in[11];
  const float* w_v    = (const float*)d_in[12];
  const float* w_proj = (const float*)d_in[13];
  float* outp = (float*)d_out;

  auto need = [](int tc)->size_t{
    return 4ull*5*PT + 8ull*tc*O3 + 8ull*tc*CC
         + 16ull*tc*O3*NRG + 16ull*tc*CC*NRG
         + 6ull*WTOT
         + 10ull*tc*PT
         + 4ull*tc*BN*O3;
  };
  int TC = 16;
  while (TC > 1 && need(TC) > ws_size) TC >>= 1;

  char* p = (char*)d_ws;
  float* vin = (float*)p; p += 4ull*PT;
  float* vq  = (float*)p; p += 4ull*PT;
  float* vk  = (float*)p; p += 4ull*PT;
  float* vv  = (float*)p; p += 4ull*PT;
  float* vo  = (float*)p; p += 4ull*PT;
  float* mean1 = (float*)p; p += 4ull*TC*O3;
  float* rstd1 = (float*)p; p += 4ull*TC*O3;
  float* mean2 = (float*)p; p += 4ull*TC*CC;
  float* rstd2 = (float*)p; p += 4ull*TC*CC;
  double* p1sum = (double*)p; p += 8ull*TC*O3*NRG;
  double* p1sq  = (double*)p; p += 8ull*TC*O3*NRG;
  double* p2sum = (double*)p; p += 8ull*TC*CC*NRG;
  double* p2sq  = (double*)p; p += 8ull*TC*CC*NRG;
  u16* whi  = (u16*)p; p += 2ull*WTOT;
  u16* wmid = (u16*)p; p += 2ull*WTOT;
  u16* wlo  = (u16*)p; p += 2ull*WTOT;
  u16* s0    = (u16*)p; p += 2ull*TC*PT;
  u16* qsb   = (u16*)p; p += 2ull*TC*PT;
  u16* ksb   = (u16*)p; p += 2ull*TC*PT;
  u16* vsb   = (u16*)p; p += 2ull*TC*PT;
  u16* sproj = (u16*)p; p += 2ull*TC*PT;
  float* qkv_all = (float*)p;                 // tc*BN*O3 floats
  float* attn    = qkv_all;                   // tc*PT (overlaps dead qkv_all)
  float* projo   = qkv_all + (size_t)TC*PT;   // tc*PT

  k_wsplit<<<WTOT/256, 256, 0, stream>>>(qkv_w, proj_w, whi, wmid, wlo);

  for (int t0=0; t0<TT; t0+=TC){
    int M = TC*BN;
    int nMB = (M+127)/128;
    k_lif_x<<<PT/256, 256, 0, stream>>>(x, w_in, vin, s0, t0, TC);

    k_gemm_mfma<O3><<<nMB*(O3/128), 256, 0, stream>>>(
        s0, whi, wmid, wlo, qkv_b, qkv_all, M);

    k_stat_part<O3><<<dim3(O3/64, TC, NRG), dim3(64,4), 0, stream>>>(qkv_all, p1sum, p1sq);
    if (TC == 16)
      k_stat_reduce<O3,16><<<(16*O3+255)/256, 256, 0, stream>>>(p1sum, p1sq, mean1, rstd1);
    else if (TC == 8)
      k_stat_reduce<O3,8><<<(8*O3+255)/256, 256, 0, stream>>>(p1sum, p1sq, mean1, rstd1);
    else
      k_stat_reduce<O3,4><<<(4*O3+255)/256, 256, 0, stream>>>(p1sum, p1sq, mean1, rstd1);

    k_lif_qkv<<<dim3(PT/256, 3), 256, 0, stream>>>(qkv_all, mean1, rstd1, bn1_g, bn1_b,
                                                   w_q, w_k, w_v, vq, vk, vv,
                                                   qsb, ksb, vsb, t0, TC);

    k_kvqv_mfma<<<TC*BB*HH, 256, 0, stream>>>(ksb, vsb, qsb, attn);

    k_lif_attn<<<PT/256, 256, 0, stream>>>(attn, w_proj, vo, sproj, t0, TC);

    k_gemm_mfma<CC><<<nMB*(CC/128), 256, 0, stream>>>(
        sproj, whi + (size_t)O3*CC, wmid + (size_t)O3*CC, wlo + (size_t)O3*CC,
        proj_b, projo, M);

    k_stat_part<CC><<<dim3(CC/64, TC, NRG), dim3(64,4), 0, stream>>>(projo, p2sum, p2sq);
    if (TC == 16)
      k_stat_reduce<CC,16><<<(16*CC+255)/256, 256, 0, stream>>>(p2sum, p2sq, mean2, rstd2);
    else if (TC == 8)
      k_stat_reduce<CC,8><<<(8*CC+255)/256, 256, 0, stream>>>(p2sum, p2sq, mean2, rstd2);
    else
      k_stat_reduce<CC,4><<<(4*CC+255)/256, 256, 0, stream>>>(p2sum, p2sq, mean2, rstd2);

    k_bn2_apply<<<(TC*(size_t)PT)/1024, 256, 0, stream>>>(projo, mean2, rstd2,
                                                          bn2_g, bn2_b, outp, t0);
  }
}